// Round 8
// baseline (1702.841 us; speedup 1.0000x reference)
//
#include <hip/hip_runtime.h>

// GlobalNet conv-GRU on MI355X — round 8.
// r6/r7 post-mortem: bottleneck is VMEM instruction issue (TA port ~16 cyc per
// 1KB wave load), invariant across r5/r6/r7 at ~1050 B-loads/CU/step. Fix:
// double MFMA-per-B-load via m_frags 2->4. Wave tile 64m x 48n; block = 5 waves,
// 64 m-rows x j-half; grid 256 = 128 m-blocks x 2 j-halves = 1 block/CU.

#define Bn   16
#define Tn   64
#define Ln   512
#define Cn   64
#define Hn   150
#define G3   450
#define SW   160
#define HP   160    // padded hidden
#define KCH  25     // k-chunks (32) for h GEMM (K=800)
#define KCX  10     // k-chunks for x GEMM (K=320)
#define Mtot 8192   // Bn*Ln

typedef __bf16 bf16x8 __attribute__((ext_vector_type(8)));
typedef float  f32x4  __attribute__((ext_vector_type(4)));
typedef short  s16x4  __attribute__((ext_vector_type(4)));

__device__ inline short f2bf(float f) {
  unsigned u = __builtin_bit_cast(unsigned, f);
  u += 0x7fffu + ((u >> 16) & 1u);   // RNE (finite inputs)
  return (short)(u >> 16);
}

// Packed B layout: [nt (n/16)][kc][lane (quad*16+l16)][j (8)] shorts.
// Fragment element: B[k = kc*32+quad*8+j][n = nt*16+l16].
// n maps (seg=n/160, jl=n%160) -> orig col seg*150+jl (zero pad elsewhere).
__global__ __launch_bounds__(256) void pack_weights(const float* __restrict__ ki,
                                                    const float* __restrict__ kh,
                                                    short* __restrict__ Bx,
                                                    short* __restrict__ Bh) {
  int idx = blockIdx.x * 256 + threadIdx.x;
  if (idx < 32 * KCH * 512) {
    int j = idx & 7, lane = (idx >> 3) & 63;
    int rest = idx >> 9;
    int kc = rest % KCH, nt = rest / KCH;
    int quad = lane >> 4, l16 = lane & 15;
    int n = nt * 16 + l16, seg = n / SW, jl = n - seg * SW;
    int kk = kc / 5, jj = (kc - kk * 5) * 32 + quad * 8 + j;
    float v = (seg < 3 && jl < Hn && jj < Hn) ? kh[(kk * Hn + jj) * G3 + seg * Hn + jl] : 0.f;
    Bh[idx] = f2bf(v);
  } else {
    int r = idx - 32 * KCH * 512;
    if (r < 32 * KCX * 512) {
      int j = r & 7, lane = (r >> 3) & 63;
      int rest = r >> 9;
      int kc = rest % KCX, nt = rest / KCX;
      int quad = lane >> 4, l16 = lane & 15;
      int n = nt * 16 + l16, seg = n / SW, jl = n - seg * SW;
      int kk = kc / 2, cc = (kc - kk * 2) * 32 + quad * 8 + j;
      float v = (seg < 3 && jl < Hn) ? ki[(kk * Cn + cc) * G3 + seg * Hn + jl] : 0.f;
      Bx[r] = f2bf(v);
    }
  }
}

// Fully-fused recurrent step. Grid 256 = 128 m-blocks (64 rows) x 2 j-halves,
// 320 threads (5 waves). Wave w = jt: 4 m-frags x 3 segment n-tiles
// {nhalf*5+w, +10, +20} + axn. K = 800(h) + 320(x). 1 block/CU.
__global__ __launch_bounds__(320, 2)
void gru_step(const short* __restrict__ hbin, short* __restrict__ hbout,
              float* __restrict__ hf, const short* __restrict__ Bh,
              const short* __restrict__ Bx, const float* __restrict__ xs, int t) {
  __shared__ short awh[68 * 168];   // h window rows l0-2..l0+65, 160 ch (22.9 KB)
  __shared__ short awx[68 * 72];    // x window, 64 ch (9.8 KB)
  const int tid   = threadIdx.x;
  const int nhalf = blockIdx.x & 1;
  const int mblk  = blockIdx.x >> 1;
  const int bb    = mblk >> 3;
  const int l0    = (mblk & 7) * 64;

  for (int i = tid; i < 68 * 40; i += 320) {
    int r = i / 40, c4 = (i - r * 40) * 4;
    int l = l0 - 2 + r;
    s16x4 v = {0, 0, 0, 0};
    if (l >= 0 && l < Ln) v = *(const s16x4*)&hbin[((size_t)bb * Ln + l) * HP + c4];
    *(s16x4*)&awh[r * 168 + c4] = v;
  }
  for (int i = tid; i < 68 * 16; i += 320) {
    int r = i >> 4, c4 = (i & 15) * 4;
    int l = l0 - 2 + r;
    s16x4 v = {0, 0, 0, 0};
    if (l >= 0 && l < Ln) {
      f32x4 f = *(const f32x4*)&xs[(((size_t)bb * Tn + t) * Ln + l) * Cn + c4];
      v[0] = f2bf(f[0]); v[1] = f2bf(f[1]); v[2] = f2bf(f[2]); v[3] = f2bf(f[3]);
    }
    *(s16x4*)&awx[r * 72 + c4] = v;
  }
  __syncthreads();

  const int lane = tid & 63, w = tid >> 6;   // w = jt in 0..4
  const int quad = lane >> 4, l16 = lane & 15;

  const short* Bph[3];
  const short* Bpx[3];
#pragma unroll
  for (int g = 0; g < 3; ++g) {
    const int nt = g * 10 + nhalf * 5 + w;
    Bph[g] = Bh + (size_t)nt * (KCH * 512) + lane * 8;
    Bpx[g] = Bx + (size_t)nt * (KCX * 512) + lane * 8;
  }
  const int arh = l16 * 168 + quad * 8;
  const int arx = l16 * 72 + quad * 8;

  f32x4 acc[4][3] = {};   // 4 m-frags x (r | z | n(h-part))
  f32x4 axn[4] = {};      // n(x-part): n = tanh(iin + r*hin)

  // Prime x-phase B loads early (independent of the h loop — deep in flight).
  bf16x8 bx[3][3];
#pragma unroll
  for (int s = 0; s < 2; ++s)
#pragma unroll
    for (int g = 0; g < 3; ++g) bx[s][g] = *(const bf16x8*)(Bpx[g] + s * 512);

  bf16x8 bh[4][3];   // 4-stage rolling prefetch
#pragma unroll
  for (int s = 0; s < 3; ++s)
#pragma unroll
    for (int g = 0; g < 3; ++g) bh[s][g] = *(const bf16x8*)(Bph[g] + s * 512);

#pragma unroll
  for (int kc = 0; kc < KCH; ++kc) {
    const int cur = kc & 3;
    if (kc + 3 < KCH) {
      const int nxt = (kc + 3) & 3;
#pragma unroll
      for (int g = 0; g < 3; ++g)
        bh[nxt][g] = *(const bf16x8*)(Bph[g] + (kc + 3) * 512);
    }
    const int kk = kc / 5, jj = (kc - kk * 5) * 32;
    const short* ar = &awh[arh + kk * 168 + jj];
    bf16x8 a[4];
#pragma unroll
    for (int f = 0; f < 4; ++f) a[f] = *(const bf16x8*)(ar + f * 16 * 168);
#pragma unroll
    for (int f = 0; f < 4; ++f)
#pragma unroll
      for (int g = 0; g < 3; ++g)
        acc[f][g] = __builtin_amdgcn_mfma_f32_16x16x32_bf16(a[f], bh[cur][g], acc[f][g], 0, 0, 0);
  }

#pragma unroll
  for (int kc = 0; kc < KCX; ++kc) {
    const int cur = kc % 3;
    if (kc + 2 < KCX) {
      const int nxt = (kc + 2) % 3;
#pragma unroll
      for (int g = 0; g < 3; ++g)
        bx[nxt][g] = *(const bf16x8*)(Bpx[g] + (kc + 2) * 512);
    }
    const int kk = kc >> 1, jj = (kc & 1) * 32;
    const short* ar = &awx[arx + kk * 72 + jj];
    bf16x8 a[4];
#pragma unroll
    for (int f = 0; f < 4; ++f) a[f] = *(const bf16x8*)(ar + f * 16 * 72);
#pragma unroll
    for (int f = 0; f < 4; ++f) {
      acc[f][0] = __builtin_amdgcn_mfma_f32_16x16x32_bf16(a[f], bx[cur][0], acc[f][0], 0, 0, 0);
      acc[f][1] = __builtin_amdgcn_mfma_f32_16x16x32_bf16(a[f], bx[cur][1], acc[f][1], 0, 0, 0);
      axn[f]    = __builtin_amdgcn_mfma_f32_16x16x32_bf16(a[f], bx[cur][2], axn[f], 0, 0, 0);
    }
  }

  // Gates: lane covers j = nhalf*80 + w*16 + l16; m-rows f*16 + quad*4 + r.
  const int j = nhalf * 80 + w * 16 + l16;
  if (j < Hn) {
#pragma unroll
    for (int f = 0; f < 4; ++f)
#pragma unroll
      for (int r = 0; r < 4; ++r) {
        const int ml = f * 16 + quad * 4 + r;
        const size_t mrow = (size_t)bb * Ln + l0 + ml;
        float rg = 1.f / (1.f + __expf(-acc[f][0][r]));
        float zg = 1.f / (1.f + __expf(-acc[f][1][r]));
        float xg = axn[f][r] + rg * acc[f][2][r];
        xg = fminf(fmaxf(xg, -15.f), 15.f);
        float e = __expf(2.f * xg);
        float n = (e - 1.f) / (e + 1.f);
        float hn = (1.f - zg) * n + zg * hf[mrow * Hn + j];
        hf[mrow * Hn + j] = hn;
        hbout[mrow * HP + j] = f2bf(hn);
      }
  }
}

// Head: thread-per-output fp32.
__global__ __launch_bounds__(256) void head1(const float* __restrict__ hf,
                                             const float* __restrict__ W1,
                                             const float* __restrict__ b1,
                                             float* __restrict__ hdn) {
  int idx = blockIdx.x * 256 + threadIdx.x;
  if (idx >= Mtot * Hn) return;
  int m = idx / Hn, j = idx - m * Hn;
  const float* hr = hf + (size_t)m * Hn;
  float acc = b1[j];
#pragma unroll 10
  for (int i = 0; i < Hn; ++i) acc = fmaf(hr[i], W1[i * Hn + j], acc);
  hdn[idx] = acc / (1.f + __expf(-acc));   // silu
}
__global__ __launch_bounds__(256) void head2(const float* __restrict__ hdn,
                                             const float* __restrict__ W2,
                                             const float* __restrict__ b2,
                                             float* __restrict__ out) {
  int idx = blockIdx.x * 256 + threadIdx.x;
  if (idx >= Mtot * 24) return;
  int m = idx / 24, j = idx - m * 24;
  const float* hr = hdn + (size_t)m * Hn;
  float acc = b2[j];
#pragma unroll 10
  for (int i = 0; i < Hn; ++i) acc = fmaf(hr[i], W2[i * 24 + j], acc);
  out[idx] = acc;
}

extern "C" void kernel_launch(void* const* d_in, const int* in_sizes, int n_in,
                              void* d_out, int out_size, void* d_ws, size_t ws_size,
                              hipStream_t stream) {
  const float* xs = (const float*)d_in[0];
  const float* ki = (const float*)d_in[1];
  const float* kh = (const float*)d_in[2];
  const float* W1 = (const float*)d_in[3];
  const float* b1 = (const float*)d_in[4];
  const float* W2 = (const float*)d_in[5];
  const float* b2 = (const float*)d_in[6];
  float* out = (float*)d_out;

  char* p = (char*)d_ws;
  float* hf  = (float*)p; p += (size_t)Mtot * Hn * 4;       // 4.7 MiB
  float* hdn = (float*)p; p += (size_t)Mtot * Hn * 4;       // 4.7 MiB
  short* hbA = (short*)p; p += (size_t)Mtot * HP * 2;       // 2.5 MiB
  short* hbB = (short*)p; p += (size_t)Mtot * HP * 2;       // 2.5 MiB
  short* Bh  = (short*)p; p += (size_t)32 * KCH * 512 * 2;  // 0.8 MiB
  short* Bx  = (short*)p; p += (size_t)32 * KCX * 512 * 2;  // 0.3 MiB

  hipMemsetAsync(hf, 0, (size_t)Mtot * Hn * 4, stream);
  hipMemsetAsync(hbA, 0, (size_t)Mtot * HP * 2 * 2, stream);  // both buffers; pads stay 0
  pack_weights<<<(32 * (KCH + KCX) * 512 + 255) / 256, 256, 0, stream>>>(ki, kh, Bx, Bh);

  for (int t = 0; t < Tn; ++t) {
    short* hin  = (t & 1) ? hbB : hbA;
    short* hout = (t & 1) ? hbA : hbB;
    gru_step<<<256, 320, 0, stream>>>(hin, hout, hf, Bh, Bx, xs, t);
  }
  head1<<<(Mtot * Hn + 255) / 256, 256, 0, stream>>>(hf, W1, b1, hdn);
  head2<<<(Mtot * 24 + 255) / 256, 256, 0, stream>>>(hdn, W2, b2, out);
}

// Round 9
// 1413.319 us; speedup vs baseline: 1.2049x; 1.2049x over previous
//
#include <hip/hip_runtime.h>

// GlobalNet conv-GRU on MI355X — round 9.
// r6-r8 post-mortem: per-CU L1 B-traffic (~1.07 MB/step ~ 7 us at 64 B/cyc) is
// the serial floor; cutting it requires m_frags=4 (r8) WITHOUT losing 10
// waves/CU (r8 died at 1.25 waves/SIMD). Fix: K-SPLIT waves. Block = 64m x
// 240n (j-half), 10 waves = (ks in {0,1}) x (jt 0..4); each wave: 4 m-frags x
// 3 segments over HALF of K (h: 13 kc each, Bh K-padded to 26 with a zero
// chunk; x: 5 kc each). Partials merged via 80 KB LDS, ks=0 computes gates.
// Per-CU B-bytes halve to ~530 KB with TLP unchanged vs r5.

#define Bn   16
#define Tn   64
#define Ln   512
#define Cn   64
#define Hn   150
#define G3   450
#define SW   160
#define HP   160    // padded hidden
#define KCH  25     // real h k-chunks (K=800)
#define KCHP 26     // padded (chunk 25 = zeros)
#define KCX  10     // x k-chunks (K=320)
#define Mtot 8192   // Bn*Ln

typedef __bf16 bf16x8 __attribute__((ext_vector_type(8)));
typedef float  f32x4  __attribute__((ext_vector_type(4)));
typedef short  s16x4  __attribute__((ext_vector_type(4)));

#define MFMA_B16(a, b, c) __builtin_amdgcn_mfma_f32_16x16x32_bf16((a), (b), (c), 0, 0, 0)

__device__ inline short f2bf(float f) {
  unsigned u = __builtin_bit_cast(unsigned, f);
  u += 0x7fffu + ((u >> 16) & 1u);   // RNE (finite inputs)
  return (short)(u >> 16);
}

// Packed B layout: [nt (n/16)][kc][lane (quad*16+l16)][j (8)] shorts.
// Fragment element: B[k = kc*32+quad*8+j][n = nt*16+l16].
// n maps (seg=n/160, jl=n%160) -> orig col seg*150+jl (zero pad elsewhere).
// Bh has KCHP=26 kc per nt; kc==25 is all zeros (K-split ghost chunk).
__global__ __launch_bounds__(256) void pack_weights(const float* __restrict__ ki,
                                                    const float* __restrict__ kh,
                                                    short* __restrict__ Bx,
                                                    short* __restrict__ Bh) {
  int idx = blockIdx.x * 256 + threadIdx.x;
  if (idx < 32 * KCHP * 512) {
    int j = idx & 7, lane = (idx >> 3) & 63;
    int rest = idx >> 9;
    int kc = rest % KCHP, nt = rest / KCHP;
    int quad = lane >> 4, l16 = lane & 15;
    int n = nt * 16 + l16, seg = n / SW, jl = n - seg * SW;
    int kk = kc / 5, jj = (kc - kk * 5) * 32 + quad * 8 + j;
    float v = (kc < KCH && seg < 3 && jl < Hn && jj < Hn)
                ? kh[(kk * Hn + jj) * G3 + seg * Hn + jl] : 0.f;
    Bh[idx] = f2bf(v);
  } else {
    int r = idx - 32 * KCHP * 512;
    if (r < 32 * KCX * 512) {
      int j = r & 7, lane = (r >> 3) & 63;
      int rest = r >> 9;
      int kc = rest % KCX, nt = rest / KCX;
      int quad = lane >> 4, l16 = lane & 15;
      int n = nt * 16 + l16, seg = n / SW, jl = n - seg * SW;
      int kk = kc / 2, cc = (kc - kk * 2) * 32 + quad * 8 + j;
      float v = (seg < 3 && jl < Hn) ? ki[(kk * Cn + cc) * G3 + seg * Hn + jl] : 0.f;
      Bx[r] = f2bf(v);
    }
  }
}

// h-phase: 13 k-chunks starting at KB (compile-time), 3-stage rolling B prefetch.
template <int KB>
__device__ __forceinline__ void h_phase(const short* __restrict__ awh, int arh,
                                        const short* const (&Bp)[3], f32x4 (&acc)[4][3]) {
  bf16x8 bh[3][3];
#pragma unroll
  for (int s = 0; s < 3; ++s)
#pragma unroll
    for (int g = 0; g < 3; ++g) bh[s][g] = *(const bf16x8*)(Bp[g] + (KB + s) * 512);
#pragma unroll
  for (int i = 0; i < 13; ++i) {
    const int kc = KB + i;
    const int kk = kc / 5, jj = (kc - kk * 5) * 32;
    const short* ar = awh + arh + kk * 168 + jj;
    const int cur = i % 3;
#pragma unroll
    for (int f = 0; f < 4; ++f) {
      bf16x8 a = *(const bf16x8*)(ar + f * 16 * 168);
      acc[f][0] = MFMA_B16(a, bh[cur][0], acc[f][0]);
      acc[f][1] = MFMA_B16(a, bh[cur][1], acc[f][1]);
      acc[f][2] = MFMA_B16(a, bh[cur][2], acc[f][2]);
    }
    if (i + 3 < 13) {
#pragma unroll
      for (int g = 0; g < 3; ++g) bh[cur][g] = *(const bf16x8*)(Bp[g] + (kc + 3) * 512);
    }
  }
}

// x-phase: 5 k-chunks starting at XB, 2-stage rolling prefetch.
template <int XB>
__device__ __forceinline__ void x_phase(const short* __restrict__ awx, int arx,
                                        const short* const (&Bp)[3],
                                        f32x4 (&acc)[4][3], f32x4 (&axn)[4]) {
  bf16x8 bx[2][3];
#pragma unroll
  for (int s = 0; s < 2; ++s)
#pragma unroll
    for (int g = 0; g < 3; ++g) bx[s][g] = *(const bf16x8*)(Bp[g] + (XB + s) * 512);
#pragma unroll
  for (int i = 0; i < 5; ++i) {
    const int kc = XB + i;
    const int kk = kc >> 1, jj = (kc & 1) * 32;
    const short* ar = awx + arx + kk * 72 + jj;
    const int cur = i % 2;
#pragma unroll
    for (int f = 0; f < 4; ++f) {
      bf16x8 a = *(const bf16x8*)(ar + f * 16 * 72);
      acc[f][0] = MFMA_B16(a, bx[cur][0], acc[f][0]);
      acc[f][1] = MFMA_B16(a, bx[cur][1], acc[f][1]);
      axn[f]    = MFMA_B16(a, bx[cur][2], axn[f]);
    }
    if (i + 2 < 5) {
#pragma unroll
      for (int g = 0; g < 3; ++g) bx[cur][g] = *(const bf16x8*)(Bp[g] + (kc + 2) * 512);
    }
  }
}

// Fused recurrent step. Grid 256 = 128 m-blocks (64 rows) x 2 j-halves,
// 640 threads (10 waves) = (ks in {0,1}) x (jt in 0..4). 1 block/CU.
__global__ __launch_bounds__(640, 3)
void gru_step(const short* __restrict__ hbin, short* __restrict__ hbout,
              float* __restrict__ hf, const short* __restrict__ Bh,
              const short* __restrict__ Bx, const float* __restrict__ xs, int t) {
  __shared__ short awh[70 * 168];   // rows l0-2..l0+65 (68 real + 2 ghost for pad kc)
  __shared__ short awx[68 * 72];
  __shared__ f32x4 red[5 * 64 * 16];  // 80 KB partial-acc exchange [v][jt][lane]
  const int tid   = threadIdx.x;
  const int nhalf = blockIdx.x & 1;
  const int mblk  = blockIdx.x >> 1;
  const int bb    = mblk >> 3;
  const int l0    = (mblk & 7) * 64;

  for (int i = tid; i < 68 * 40; i += 640) {
    int r = i / 40, c4 = (i - r * 40) * 4;
    int l = l0 - 2 + r;
    s16x4 v = {0, 0, 0, 0};
    if (l >= 0 && l < Ln) v = *(const s16x4*)&hbin[((size_t)bb * Ln + l) * HP + c4];
    *(s16x4*)&awh[r * 168 + c4] = v;
  }
  for (int i = tid; i < 68 * 16; i += 640) {
    int r = i >> 4, c4 = (i & 15) * 4;
    int l = l0 - 2 + r;
    s16x4 v = {0, 0, 0, 0};
    if (l >= 0 && l < Ln) {
      f32x4 f = *(const f32x4*)&xs[(((size_t)bb * Tn + t) * Ln + l) * Cn + c4];
      v[0] = f2bf(f[0]); v[1] = f2bf(f[1]); v[2] = f2bf(f[2]); v[3] = f2bf(f[3]);
    }
    *(s16x4*)&awx[r * 72 + c4] = v;
  }
  __syncthreads();

  const int lane = tid & 63, w = tid >> 6;
  const int jt = w % 5, ks = w / 5;
  const int quad = lane >> 4, l16 = lane & 15;

  const short* Bph[3];
#pragma unroll
  for (int g = 0; g < 3; ++g)
    Bph[g] = Bh + (size_t)(g * 10 + nhalf * 5 + jt) * (KCHP * 512) + lane * 8;
  const int arh = l16 * 168 + quad * 8;
  const int arx = l16 * 72 + quad * 8;

  f32x4 acc[4][3] = {};   // 4 m-frags x (r | z | n(h-part))
  f32x4 axn[4] = {};      // n(x-part): n = tanh(iin + r*hin)

  if (ks == 0) h_phase<0>(awh, arh, Bph, acc);
  else         h_phase<13>(awh, arh, Bph, acc);   // kc 25 = zero pad chunk

  const short* Bpx[3];
#pragma unroll
  for (int g = 0; g < 3; ++g)
    Bpx[g] = Bx + (size_t)(g * 10 + nhalf * 5 + jt) * (KCX * 512) + lane * 8;

  if (ks == 0) x_phase<0>(awx, arx, Bpx, acc, axn);
  else         x_phase<5>(awx, arx, Bpx, acc, axn);

  // Merge K-split partials: ks=1 writes, ks=0 adds.
  if (ks == 1) {
#pragma unroll
    for (int f = 0; f < 4; ++f) {
      red[((f * 4 + 0) * 5 + jt) * 64 + lane] = acc[f][0];
      red[((f * 4 + 1) * 5 + jt) * 64 + lane] = acc[f][1];
      red[((f * 4 + 2) * 5 + jt) * 64 + lane] = acc[f][2];
      red[((f * 4 + 3) * 5 + jt) * 64 + lane] = axn[f];
    }
  }
  __syncthreads();
  if (ks == 0) {
#pragma unroll
    for (int f = 0; f < 4; ++f) {
      acc[f][0] += red[((f * 4 + 0) * 5 + jt) * 64 + lane];
      acc[f][1] += red[((f * 4 + 1) * 5 + jt) * 64 + lane];
      acc[f][2] += red[((f * 4 + 2) * 5 + jt) * 64 + lane];
      axn[f]    += red[((f * 4 + 3) * 5 + jt) * 64 + lane];
    }
    // Gates: lane covers j = nhalf*80 + jt*16 + l16; m-rows f*16 + quad*4 + r.
    const int j = nhalf * 80 + jt * 16 + l16;
    if (j < Hn) {
#pragma unroll
      for (int f = 0; f < 4; ++f)
#pragma unroll
        for (int r = 0; r < 4; ++r) {
          const int ml = f * 16 + quad * 4 + r;
          const size_t mrow = (size_t)bb * Ln + l0 + ml;
          float rg = 1.f / (1.f + __expf(-acc[f][0][r]));
          float zg = 1.f / (1.f + __expf(-acc[f][1][r]));
          float xg = axn[f][r] + rg * acc[f][2][r];
          xg = fminf(fmaxf(xg, -15.f), 15.f);
          float e = __expf(2.f * xg);
          float n = (e - 1.f) / (e + 1.f);
          float hn = (1.f - zg) * n + zg * hf[mrow * Hn + j];
          hf[mrow * Hn + j] = hn;
          hbout[mrow * HP + j] = f2bf(hn);
        }
    }
  }
}

// Head: thread-per-output fp32.
__global__ __launch_bounds__(256) void head1(const float* __restrict__ hf,
                                             const float* __restrict__ W1,
                                             const float* __restrict__ b1,
                                             float* __restrict__ hdn) {
  int idx = blockIdx.x * 256 + threadIdx.x;
  if (idx >= Mtot * Hn) return;
  int m = idx / Hn, j = idx - m * Hn;
  const float* hr = hf + (size_t)m * Hn;
  float acc = b1[j];
#pragma unroll 10
  for (int i = 0; i < Hn; ++i) acc = fmaf(hr[i], W1[i * Hn + j], acc);
  hdn[idx] = acc / (1.f + __expf(-acc));   // silu
}
__global__ __launch_bounds__(256) void head2(const float* __restrict__ hdn,
                                             const float* __restrict__ W2,
                                             const float* __restrict__ b2,
                                             float* __restrict__ out) {
  int idx = blockIdx.x * 256 + threadIdx.x;
  if (idx >= Mtot * 24) return;
  int m = idx / 24, j = idx - m * 24;
  const float* hr = hdn + (size_t)m * Hn;
  float acc = b2[j];
#pragma unroll 10
  for (int i = 0; i < Hn; ++i) acc = fmaf(hr[i], W2[i * 24 + j], acc);
  out[idx] = acc;
}

extern "C" void kernel_launch(void* const* d_in, const int* in_sizes, int n_in,
                              void* d_out, int out_size, void* d_ws, size_t ws_size,
                              hipStream_t stream) {
  const float* xs = (const float*)d_in[0];
  const float* ki = (const float*)d_in[1];
  const float* kh = (const float*)d_in[2];
  const float* W1 = (const float*)d_in[3];
  const float* b1 = (const float*)d_in[4];
  const float* W2 = (const float*)d_in[5];
  const float* b2 = (const float*)d_in[6];
  float* out = (float*)d_out;

  char* p = (char*)d_ws;
  float* hf  = (float*)p; p += (size_t)Mtot * Hn * 4;        // 4.7 MiB
  float* hdn = (float*)p; p += (size_t)Mtot * Hn * 4;        // 4.7 MiB
  short* hbA = (short*)p; p += (size_t)Mtot * HP * 2;        // 2.5 MiB
  short* hbB = (short*)p; p += (size_t)Mtot * HP * 2;        // 2.5 MiB
  short* Bh  = (short*)p; p += (size_t)32 * KCHP * 512 * 2;  // 0.85 MiB
  short* Bx  = (short*)p; p += (size_t)32 * KCX * 512 * 2;   // 0.3 MiB

  hipMemsetAsync(hf, 0, (size_t)Mtot * Hn * 4, stream);
  hipMemsetAsync(hbA, 0, (size_t)Mtot * HP * 2 * 2, stream);  // both buffers; pads stay 0
  pack_weights<<<(32 * (KCHP + KCX) * 512 + 255) / 256, 256, 0, stream>>>(ki, kh, Bx, Bh);

  for (int t = 0; t < Tn; ++t) {
    short* hin  = (t & 1) ? hbB : hbA;
    short* hout = (t & 1) ? hbA : hbB;
    gru_step<<<256, 640, 0, stream>>>(hin, hout, hf, Bh, Bx, xs, t);
  }
  head1<<<(Mtot * Hn + 255) / 256, 256, 0, stream>>>(hf, W1, b1, hdn);
  head2<<<(Mtot * 24 + 255) / 256, 256, 0, stream>>>(hdn, W2, b2, out);
}